// Round 7
// baseline (517.630 us; speedup 1.0000x reference)
//
#include <hip/hip_runtime.h>

typedef _Float16 h4 __attribute__((ext_vector_type(4)));
typedef _Float16 h8 __attribute__((ext_vector_type(8)));
typedef float f4 __attribute__((ext_vector_type(4)));

#define MFMA16(a, b, c) __builtin_amdgcn_mfma_f32_16x16x32_f16((a), (b), (c), 0, 0, 0)

static constexpr int TT  = 1024;
static constexpr int BS  = 1024;
static constexpr int LCH = 32;   // chunk length
static constexpr int NCH = 32;   // chunks (16 per half)
static constexpr size_t XTOT = (size_t)TT * BS * 128;

// workspace byte offsets
static constexpr size_t WS_WT16 = 0;       // 128x128 f16 : W_eff^T (S row-major)
static constexpr size_t WS_HF1  = 32768;   // 128x64  f16
static constexpr size_t WS_HF2  = 49152;   // 64x128  f16
static constexpr size_t WS_BW   = 65536;   // 128x64  f16
static constexpr size_t WS_EW   = 81920;   // 128x32  f16
static constexpr size_t WS_W32  = 90112;   // 128x128 f16 : (W^32)^T layout
static constexpr size_t WS_F    = 131072;                                // NCH slots f32
static constexpr size_t WS_INIT = WS_F + (size_t)NCH * BS * 128 * 4;     // NCH slots f32
static constexpr size_t WS_DRV  = WS_INIT + (size_t)NCH * BS * 128 * 4;  // 134 MB f16/half
// Drv (per half): h8-index = ((tl*64 + bt)*4 + p)*64 + lane, tl = t - half*512

template <typename T>
__device__ inline T ntload(const T* p) { return __builtin_nontemporal_load(p); }

// ---------------------------------------------------------------------------
// prep: W_eff (softmax+scale, stored transposed = S row-major) + f16 weights
// ---------------------------------------------------------------------------
__global__ void prep_kernel(const float* __restrict__ Aw, const float* __restrict__ As,
                            const float* __restrict__ hf1, const float* __restrict__ hf2,
                            const float* __restrict__ Bw, const float* __restrict__ Ew,
                            char* __restrict__ ws)
{
    const int tid = threadIdx.x;  // 128
    const int bid = blockIdx.x;   // 160
    if (bid < 128) {
        __shared__ float red[128];
        const int n = bid;
        const float a = Aw[n * 128 + tid];
        red[tid] = a;
        __syncthreads();
        for (int s = 64; s > 0; s >>= 1) {
            if (tid < s) red[tid] = fmaxf(red[tid], red[tid + s]);
            __syncthreads();
        }
        const float mx = red[0];
        __syncthreads();
        const float e = expf(a - mx);
        red[tid] = e;
        __syncthreads();
        for (int s = 64; s > 0; s >>= 1) {
            if (tid < s) red[tid] += red[tid + s];
            __syncthreads();
        }
        const float sm  = e / red[0];
        const float asv = As[n * 128 + tid];
        const float sc  = 1.0f - 0.1f * (1.0f / (1.0f + expf(-asv)));
        ((_Float16*)(ws + WS_WT16))[n * 128 + tid] = (_Float16)(sc * sm);
    } else {
        const int b2 = bid - 128;  // 32 blocks
        for (int i = b2 * 128 + tid; i < 8192; i += 32 * 128) {
            ((_Float16*)(ws + WS_HF1))[i] = (_Float16)hf1[i];
            ((_Float16*)(ws + WS_HF2))[i] = (_Float16)hf2[i];
            ((_Float16*)(ws + WS_BW))[i]  = (_Float16)Bw[i];
            if (i < 4096) ((_Float16*)(ws + WS_EW))[i] = (_Float16)Ew[i];
        }
    }
}

// ---------------------------------------------------------------------------
// W^32 via 5 dual-chain squarings: keep G=(W^T)^(2^s) and H=G^T=W^(2^s).
// D = G·G fragment is a COLUMN slice (col=lane&15, rows consecutive) ->
// vector h4-write into H_next (= (G·G)^T); D2 = H·H vector-writes G_next.
// All LDS reads/writes vectorized; rows padded to 136 to spread banks.
// ---------------------------------------------------------------------------
__global__ void w32_kernel(char* __restrict__ ws)
{
    const int tid  = threadIdx.x;
    const int lane = tid & 63;
    const int w    = tid >> 6;
    const int cl   = lane & 15;
    const int gq   = lane >> 4;
    constexpr int LDP = 136;  // padded row stride (halves)

    __shared__ __align__(16) _Float16 G[2][128 * LDP];
    __shared__ __align__(16) _Float16 H[2][128 * LDP];

    const _Float16* Wt16 = (const _Float16*)(ws + WS_WT16);
    for (int i = tid; i < 2048; i += 256)
        *(h8*)&G[0][(i >> 4) * LDP + (i & 15) * 8] = *(const h8*)&Wt16[i * 8];
    __syncthreads();
    for (int i = tid; i < 16384; i += 256) {
        const int r = i >> 7, cc = i & 127;
        H[0][cc * LDP + r] = G[0][r * LDP + cc];
    }
    __syncthreads();

    int cur = 0;
    for (int s = 0; s < 5; ++s) {
        const _Float16* Gs = G[cur];
        const _Float16* Hs = H[cur];
        _Float16* Gd = G[cur ^ 1];
        _Float16* Hd = H[cur ^ 1];
        f4 aG[8][2], aH[8][2];
#pragma unroll
        for (int mt = 0; mt < 8; ++mt)
#pragma unroll
            for (int nt = 0; nt < 2; ++nt) { aG[mt][nt] = f4{}; aH[mt][nt] = f4{}; }
#pragma unroll
        for (int kk = 0; kk < 4; ++kk) {
            h8 bG0 = *(const h8*)&Hs[((w * 2 + 0) * 16 + cl) * LDP + kk * 32 + gq * 8];
            h8 bG1 = *(const h8*)&Hs[((w * 2 + 1) * 16 + cl) * LDP + kk * 32 + gq * 8];
            h8 bH0 = *(const h8*)&Gs[((w * 2 + 0) * 16 + cl) * LDP + kk * 32 + gq * 8];
            h8 bH1 = *(const h8*)&Gs[((w * 2 + 1) * 16 + cl) * LDP + kk * 32 + gq * 8];
#pragma unroll
            for (int mt = 0; mt < 8; ++mt) {
                h8 ag = *(const h8*)&Gs[(mt * 16 + cl) * LDP + kk * 32 + gq * 8];
                h8 ah = *(const h8*)&Hs[(mt * 16 + cl) * LDP + kk * 32 + gq * 8];
                aG[mt][0] = MFMA16(ag, bG0, aG[mt][0]);
                aG[mt][1] = MFMA16(ag, bG1, aG[mt][1]);
                aH[mt][0] = MFMA16(ah, bH0, aH[mt][0]);
                aH[mt][1] = MFMA16(ah, bH1, aH[mt][1]);
            }
        }
#pragma unroll
        for (int mt = 0; mt < 8; ++mt)
#pragma unroll
            for (int nt = 0; nt < 2; ++nt) {
                h4 hg, hh;
#pragma unroll
                for (int r = 0; r < 4; ++r) {
                    hg[r] = (_Float16)aG[mt][nt][r];
                    hh[r] = (_Float16)aH[mt][nt][r];
                }
                const int col  = (w * 2 + nt) * 16 + cl;
                const int rowb = mt * 16 + gq * 4;
                *(h4*)&Hd[col * LDP + rowb] = hg;   // H_next = (G·G)^T
                *(h4*)&Gd[col * LDP + rowb] = hh;   // G_next = (H·H)^T
            }
        __syncthreads();
        cur ^= 1;
    }
    _Float16* W32 = (_Float16*)(ws + WS_W32);
    for (int i = tid; i < 2048; i += 256)
        *(h8*)&W32[i * 8] = *(const h8*)&G[cur][(i >> 4) * LDP + (i & 15) * 8];
}

// ---------------------------------------------------------------------------
// K1 fused (per half): per wave = one (chunk, 16-b tile). Each step:
// MLP (weights streamed from swizzled LDS as A-operands, inputs loaded
// per-lane from global as B-fragments), drive stored to Drv (cached, for K3),
// then local-scan accumulate in registers. No barriers in the loop.
// Writes F[c] at k=31.
// ---------------------------------------------------------------------------
__global__ __launch_bounds__(256, 1)
void fused_local(const float* __restrict__ Mfl, const float* __restrict__ DTi,
                 const float* __restrict__ Din, char* __restrict__ ws, int c0)
{
    const int tid   = threadIdx.x;
    const int wslot = tid >> 6;
    const int lane  = tid & 63;
    const int cl = lane & 15, gq = lane >> 4;
    const int wid = blockIdx.x * 4 + wslot;   // 0..1023
    const int c   = c0 + (wid >> 6);          // chunk
    const int bt  = wid & 63;
    const int b0  = bt * 16;

    __shared__ __align__(16) _Float16 Lhf1[128 * 64];   // 16 KB (swizzled)
    __shared__ __align__(16) _Float16 Lhf2[64 * 128];   // 16 KB
    __shared__ __align__(16) _Float16 Lbw[128 * 64];    // 16 KB
    __shared__ __align__(16) _Float16 Lew[128 * 32];    // 8 KB
    __shared__ __align__(16) _Float16 tb[4][16 * 128];  // 16 KB

    // ---- stage weights to LDS with XOR swizzle (h8-granular)
    {
        const h8* g1 = (const h8*)(ws + WS_HF1);
        const h8* g2 = (const h8*)(ws + WS_HF2);
        const h8* gb = (const h8*)(ws + WS_BW);
        const h8* ge = (const h8*)(ws + WS_EW);
        for (int i = tid; i < 1024; i += 256) {
            const int r = i >> 3, c8 = i & 7;
            *(h8*)&Lhf1[(r * 8 + (c8 ^ (r & 7))) * 8] = g1[i];
            *(h8*)&Lbw[(r * 8 + (c8 ^ (r & 7))) * 8]  = gb[i];
        }
        for (int i = tid; i < 1024; i += 256) {
            const int r = i >> 4, c8 = i & 15;
            *(h8*)&Lhf2[(r * 16 + (c8 ^ (r & 15))) * 8] = g2[i];
        }
        for (int i = tid; i < 512; i += 256) {
            const int r = i >> 2, c8 = i & 3;
            *(h8*)&Lew[(r * 4 + (c8 ^ (r & 3))) * 8] = ge[i];
        }
    }

    // ---- scan W^T fragments (registers, from global)
    const _Float16* Wt16 = (const _Float16*)(ws + WS_WT16);
    h8 wf[8][4];
#pragma unroll
    for (int nt = 0; nt < 8; ++nt)
#pragma unroll
        for (int kt = 0; kt < 4; ++kt)
            wf[nt][kt] = *(const h8*)&Wt16[(nt * 16 + cl) * 128 + kt * 32 + gq * 8];
    __syncthreads();

    _Float16* tbuf = tb[wslot];
    _Float16* Drv  = (_Float16*)(ws + WS_DRV);
    float* Fbuf    = (float*)(ws + WS_F);

    h8 xf[4];
#pragma unroll
    for (int kt = 0; kt < 4; ++kt) xf[kt] = h8{};

    // ---- input loads (per-lane B-fragments straight from global)
    f4 Lm0, Lm1, Lt0, Lt1, Ld0, Ld1;
    auto ILOAD = [&](int k) {
        const size_t t  = (size_t)c * LCH + k;
        const size_t ba = (t * BS + b0 + cl) * 32 + gq * 8;
        Lm0 = ntload((const f4*)&Mfl[ba]);
        Lm1 = ntload((const f4*)&Mfl[ba + 4]);
        Lt0 = ntload((const f4*)&DTi[ba]);
        Lt1 = ntload((const f4*)&DTi[ba + 4]);
        Ld0 = ntload((const f4*)&Din[ba]);
        Ld1 = ntload((const f4*)&Din[ba + 4]);
    };
    h8 fm, fdt, fd;
    auto ICVT = [&]() {
#pragma unroll
        for (int j = 0; j < 4; ++j) {
            fm[j] = (_Float16)Lm0[j];  fm[4 + j] = (_Float16)Lm1[j];
            fdt[j] = (_Float16)Lt0[j]; fdt[4 + j] = (_Float16)Lt1[j];
            fd[j] = (_Float16)Ld0[j];  fd[4 + j] = (_Float16)Ld1[j];
        }
    };
    ILOAD(0);
    ICVT();

    for (int k = 0; k < LCH; ++k) {
        // ---- G1: h^T = hf1 * md^T
        f4 ah[8];
#pragma unroll
        for (int nt = 0; nt < 8; ++nt) {
            f4 z = {};
            h8 a0 = *(const h8*)&Lhf1[((nt * 16 + cl) * 8 + (gq ^ (cl & 7))) * 8];
            h8 a1 = *(const h8*)&Lhf1[((nt * 16 + cl) * 8 + ((4 + gq) ^ (cl & 7))) * 8];
            ah[nt] = MFMA16(a0, fm, z);
            ah[nt] = MFMA16(a1, fdt, ah[nt]);
        }
#pragma unroll
        for (int nt = 0; nt < 8; ++nt) {
            h4 hv;
#pragma unroll
            for (int r = 0; r < 4; ++r) hv[r] = (_Float16)fmaxf(ah[nt][r], 0.f);
            *(h4*)&tbuf[cl * 128 + (((nt * 2 + (gq >> 1)) ^ cl) & 15) * 8 + (gq & 1) * 4] = hv;
        }
        h8 hfr[4];
#pragma unroll
        for (int kt = 0; kt < 4; ++kt)
            hfr[kt] = *(const h8*)&tbuf[cl * 128 + (((kt * 4 + gq) ^ cl) & 15) * 8];

        // ---- G2: u^T = hf2 * h^T
        f4 au[4];
#pragma unroll
        for (int nt = 0; nt < 4; ++nt) {
            f4 z = {};
            au[nt] = z;
#pragma unroll
            for (int kt = 0; kt < 4; ++kt) {
                h8 a = *(const h8*)&Lhf2[((nt * 16 + cl) * 16 + ((kt * 4 + gq) ^ cl)) * 8];
                au[nt] = MFMA16(a, hfr[kt], au[nt]);
            }
        }
#pragma unroll
        for (int nt = 0; nt < 4; ++nt) {
            h4 uv;
#pragma unroll
            for (int r = 0; r < 4; ++r) uv[r] = (_Float16)fmaxf(au[nt][r], 0.f);
            const int ub8 = nt * 2 + (gq >> 1);
            *(h4*)&tbuf[cl * 128 + ((ub8 ^ (cl & 7)) & 7) * 8 + (gq & 1) * 4] = uv;
        }
        h8 ufr0 = *(const h8*)&tbuf[cl * 128 + ((gq ^ (cl & 7)) & 7) * 8];
        h8 ufr1 = *(const h8*)&tbuf[cl * 128 + (((4 + gq) ^ (cl & 7)) & 7) * 8];

        // ---- G3: drive^T = Bw*u^T + Ew*D^T  (acc = scan accumulator)
        f4 acc[8];
#pragma unroll
        for (int nt = 0; nt < 8; ++nt) {
            f4 z = {};
            h8 b0w = *(const h8*)&Lbw[((nt * 16 + cl) * 8 + (gq ^ (cl & 7))) * 8];
            h8 b1w = *(const h8*)&Lbw[((nt * 16 + cl) * 8 + ((4 + gq) ^ (cl & 7))) * 8];
            h8 ewf = *(const h8*)&Lew[((nt * 16 + cl) * 4 + (gq ^ (cl & 3))) * 8];
            acc[nt] = MFMA16(b0w, ufr0, z);
            acc[nt] = MFMA16(b1w, ufr1, acc[nt]);
            acc[nt] = MFMA16(ewf, fd, acc[nt]);
        }

        // ---- store Drv (normal stores -> L3-cached for K3)
        {
            const size_t tl = (size_t)(c - c0) * LCH + k;
#pragma unroll
            for (int p = 0; p < 4; ++p) {
                h8 o;
#pragma unroll
                for (int r = 0; r < 4; ++r) {
                    o[r]     = (_Float16)acc[2 * p][r];
                    o[4 + r] = (_Float16)acc[2 * p + 1][r];
                }
                *(h8*)&Drv[(((tl * 64 + bt) * 4 + p) * 64 + lane) * 8] = o;
            }
        }

        if (k + 1 < LCH) ILOAD(k + 1);  // prefetch under the scan MFMAs

        // ---- scan: acc += W^T x
#pragma unroll
        for (int kt = 0; kt < 4; ++kt)
#pragma unroll
            for (int nt = 0; nt < 8; ++nt)
                acc[nt] = MFMA16(wf[nt][kt], xf[kt], acc[nt]);

        if (k == LCH - 1) {
#pragma unroll
            for (int nt = 0; nt < 8; ++nt)
                *(f4*)&Fbuf[((size_t)c * BS + b0 + cl) * 128 + nt * 16 + gq * 4] = acc[nt];
        } else {
#pragma unroll
            for (int nt = 0; nt < 8; ++nt) {
                h4 hv;
#pragma unroll
                for (int r = 0; r < 4; ++r) hv[r] = (_Float16)acc[nt][r];
                *(h4*)&tbuf[cl * 128 + (((nt * 2 + (gq >> 1)) ^ cl) & 15) * 8 + (gq & 1) * 4] = hv;
            }
#pragma unroll
            for (int kt = 0; kt < 4; ++kt)
                xf[kt] = *(const h8*)&tbuf[cl * 128 + (((kt * 4 + gq) ^ cl) & 15) * 8];
            ICVT();
        }
    }
}

// ---------------------------------------------------------------------------
// K3 (per half): register scan with true inits; Drv read (L3-warm), X/Y NT.
// ---------------------------------------------------------------------------
__global__ __launch_bounds__(256, 2)
void scan_final(char* __restrict__ ws, int c0,
                float* __restrict__ Xout, float* __restrict__ Yout)
{
    const int wslot = threadIdx.x >> 6;
    const int wid   = blockIdx.x * 4 + wslot;
    const int lane  = threadIdx.x & 63;
    const int cl = lane & 15, gq = lane >> 4;
    const int c  = c0 + (wid >> 6);
    const int bt = wid & 63;
    const int b0 = bt * 16;

    const _Float16* Wt16 = (const _Float16*)(ws + WS_WT16);
    const _Float16* Drv  = (const _Float16*)(ws + WS_DRV);
    const float* Init    = (const float*)(ws + WS_INIT);

    __shared__ __align__(16) _Float16 tb[4][16 * 128];
    _Float16* tbuf = tb[wslot];

    h8 wf[8][4];
#pragma unroll
    for (int nt = 0; nt < 8; ++nt)
#pragma unroll
        for (int kt = 0; kt < 4; ++kt)
            wf[nt][kt] = *(const h8*)&Wt16[(nt * 16 + cl) * 128 + kt * 32 + gq * 8];

    h8 xf[4];
    {
        f4 iv[8];
#pragma unroll
        for (int nt = 0; nt < 8; ++nt)
            iv[nt] = *(const f4*)&Init[((size_t)c * BS + b0 + cl) * 128 + nt * 16 + gq * 4];
#pragma unroll
        for (int nt = 0; nt < 8; ++nt) {
            h4 hv;
#pragma unroll
            for (int r = 0; r < 4; ++r) hv[r] = (_Float16)iv[nt][r];
            *(h4*)&tbuf[cl * 128 + (((nt * 2 + (gq >> 1)) ^ cl) & 15) * 8 + (gq & 1) * 4] = hv;
        }
#pragma unroll
        for (int kt = 0; kt < 4; ++kt)
            xf[kt] = *(const h8*)&tbuf[cl * 128 + (((kt * 4 + gq) ^ cl) & 15) * 8];
    }

    constexpr size_t STEP = 16384;  // h8 units per t-step (64*4*64)
    const h8* dp = (const h8*)Drv + (((size_t)((c - c0) * LCH) * 64 + bt) * 4) * 64 + lane;
    h8 dra0, dra1, dra2, dra3, drb0, drb1, drb2, drb3;
    dra0 = dp[0];    dra1 = dp[64];        dra2 = dp[128];        dra3 = dp[192];
    drb0 = dp[STEP]; drb1 = dp[STEP + 64]; drb2 = dp[STEP + 128]; drb3 = dp[STEP + 192];

#define SCAN_STEP(K, D0, D1, D2, D3)                                                     \
    {                                                                                    \
        f4 acc[8];                                                                       \
        _Pragma("unroll") for (int r = 0; r < 4; ++r) {                                  \
            acc[0][r] = (float)D0[r]; acc[1][r] = (float)D0[4 + r];                      \
            acc[2][r] = (float)D1[r]; acc[3][r] = (float)D1[4 + r];                      \
            acc[4][r] = (float)D2[r]; acc[5][r] = (float)D2[4 + r];                      \
            acc[6][r] = (float)D3[r]; acc[7][r] = (float)D3[4 + r];                      \
        }                                                                                \
        if ((K) + 2 < LCH) {                                                             \
            D0 = dp[(size_t)((K) + 2) * STEP + 0];                                       \
            D1 = dp[(size_t)((K) + 2) * STEP + 64];                                      \
            D2 = dp[(size_t)((K) + 2) * STEP + 128];                                     \
            D3 = dp[(size_t)((K) + 2) * STEP + 192];                                     \
        }                                                                                \
        _Pragma("unroll") for (int kt = 0; kt < 4; ++kt)                                 \
            _Pragma("unroll") for (int nt = 0; nt < 8; ++nt)                             \
                acc[nt] = MFMA16(wf[nt][kt], xf[kt], acc[nt]);                           \
        {                                                                                \
            const size_t t = (size_t)c * LCH + (K);                                      \
            float* xp = &Xout[(t * BS + b0 + cl) * 128 + gq * 4];                        \
            _Pragma("unroll") for (int nt = 0; nt < 8; ++nt)                             \
                __builtin_nontemporal_store(acc[nt], (f4*)&xp[nt * 16]);                 \
            if (gq == 3)                                                                 \
                __builtin_nontemporal_store(acc[7][3], &Yout[t * BS + b0 + cl]);         \
        }                                                                                \
        if ((K) < LCH - 1) {                                                             \
            _Pragma("unroll") for (int nt = 0; nt < 8; ++nt) {                           \
                h4 hv;                                                                   \
                _Pragma("unroll") for (int r = 0; r < 4; ++r)                            \
                    hv[r] = (_Float16)acc[nt][r];                                        \
                *(h4*)&tbuf[cl * 128 + (((nt * 2 + (gq >> 1)) ^ cl) & 15) * 8 +          \
                            (gq & 1) * 4] = hv;                                          \
            }                                                                            \
            _Pragma("unroll") for (int kt = 0; kt < 4; ++kt)                             \
                xf[kt] = *(const h8*)&tbuf[cl * 128 + (((kt * 4 + gq) ^ cl) & 15) * 8];  \
        }                                                                                \
    }

    for (int k = 0; k < LCH; k += 2) {
        SCAN_STEP(k, dra0, dra1, dra2, dra3);
        SCAN_STEP(k + 1, drb0, drb1, drb2, drb3);
    }
#undef SCAN_STEP
}

// ---------------------------------------------------------------------------
// carry: Init[cc] = Init[cc-1] @ W^32 + F[cc-1], cc in (cc_lo, cc_lo+n_steps].
// ---------------------------------------------------------------------------
__global__ __launch_bounds__(64, 1)
void carry_kernel(const float* __restrict__ x0, char* __restrict__ ws,
                  int cc_lo, int n_steps, int copy0)
{
    const int lane = threadIdx.x;
    const int cl = lane & 15, gq = lane >> 4;
    const int b0 = blockIdx.x * 16;

    const _Float16* W32 = (const _Float16*)(ws + WS_W32);
    const float* Fbuf   = (const float*)(ws + WS_F);
    float* Init         = (float*)(ws + WS_INIT);

    __shared__ __align__(16) _Float16 tbuf[16 * 128];

    h8 wf[8][4];
#pragma unroll
    for (int nt = 0; nt < 8; ++nt)
#pragma unroll
        for (int kt = 0; kt < 4; ++kt)
            wf[nt][kt] = *(const h8*)&W32[(nt * 16 + cl) * 128 + kt * 32 + gq * 8];

    h8 xf[4];
    {
        f4 iv[8];
#pragma unroll
        for (int nt = 0; nt < 8; ++nt)
            iv[nt] = *(const f4*)&x0[(size_t)(b0 + cl) * 128 + nt * 16 + gq * 4];
        if (copy0) {
#pragma unroll
            for (int nt = 0; nt < 8; ++nt)
                *(f4*)&Init[((size_t)cc_lo * BS + b0 + cl) * 128 + nt * 16 + gq * 4] = iv[nt];
        }
#pragma unroll
        for (int nt = 0; nt < 8; ++nt) {
            h4 hv;
#pragma unroll
            for (int r = 0; r < 4; ++r) hv[r] = (_Float16)iv[nt][r];
            *(h4*)&tbuf[cl * 128 + (((nt * 2 + (gq >> 1)) ^ cl) & 15) * 8 + (gq & 1) * 4] = hv;
        }
#pragma unroll
        for (int kt = 0; kt < 4; ++kt)
            xf[kt] = *(const h8*)&tbuf[cl * 128 + (((kt * 4 + gq) ^ cl) & 15) * 8];
    }

    for (int i = 1; i <= n_steps; ++i) {
        const int cc = cc_lo + i;
        f4 acc[8];
#pragma unroll
        for (int nt = 0; nt < 8; ++nt)
            acc[nt] = *(const f4*)&Fbuf[((size_t)(cc - 1) * BS + b0 + cl) * 128 + nt * 16 + gq * 4];
#pragma unroll
        for (int kt = 0; kt < 4; ++kt)
#pragma unroll
            for (int nt = 0; nt < 8; ++nt)
                acc[nt] = MFMA16(wf[nt][kt], xf[kt], acc[nt]);
#pragma unroll
        for (int nt = 0; nt < 8; ++nt)
            *(f4*)&Init[((size_t)cc * BS + b0 + cl) * 128 + nt * 16 + gq * 4] = acc[nt];
        if (i < n_steps) {
#pragma unroll
            for (int nt = 0; nt < 8; ++nt) {
                h4 hv;
#pragma unroll
                for (int r = 0; r < 4; ++r) hv[r] = (_Float16)acc[nt][r];
                *(h4*)&tbuf[cl * 128 + (((nt * 2 + (gq >> 1)) ^ cl) & 15) * 8 + (gq & 1) * 4] = hv;
            }
#pragma unroll
            for (int kt = 0; kt < 4; ++kt)
                xf[kt] = *(const h8*)&tbuf[cl * 128 + (((kt * 4 + gq) ^ cl) & 15) * 8];
        }
    }
}

// ---------------------------------------------------------------------------
extern "C" void kernel_launch(void* const* d_in, const int* in_sizes, int n_in,
                              void* d_out, int out_size, void* d_ws, size_t ws_size,
                              hipStream_t stream)
{
    const float* x_in = (const float*)d_in[0];
    const float* Mfl  = (const float*)d_in[1];
    const float* DTi  = (const float*)d_in[2];
    const float* Din  = (const float*)d_in[3];
    const float* Aw   = (const float*)d_in[4];
    const float* As   = (const float*)d_in[5];
    const float* Bw   = (const float*)d_in[6];
    const float* Ew   = (const float*)d_in[7];
    const float* hf1  = (const float*)d_in[8];
    const float* hf2  = (const float*)d_in[9];
    char* ws    = (char*)d_ws;
    float* Xout = (float*)d_out;
    float* Yout = Xout + XTOT;
    const float* Init16 = (const float*)(ws + WS_INIT) + (size_t)16 * BS * 128;

    prep_kernel<<<dim3(160), dim3(128), 0, stream>>>(Aw, As, hf1, hf2, Bw, Ew, ws);
    w32_kernel<<<dim3(1), dim3(256), 0, stream>>>(ws);

    // ---- half 1: chunks 0..15 (t 0..511)
    fused_local<<<dim3(256), dim3(256), 0, stream>>>(Mfl, DTi, Din, ws, 0);
    carry_kernel<<<dim3(64), dim3(64), 0, stream>>>(x_in, ws, 0, 16, 1);
    scan_final<<<dim3(256), dim3(256), 0, stream>>>(ws, 0, Xout, Yout);

    // ---- half 2: chunks 16..31 (t 512..1023)
    fused_local<<<dim3(256), dim3(256), 0, stream>>>(Mfl, DTi, Din, ws, 16);
    carry_kernel<<<dim3(64), dim3(64), 0, stream>>>(Init16, ws, 16, 15, 0);
    scan_final<<<dim3(256), dim3(256), 0, stream>>>(ws, 16, Xout, Yout);
}

// Round 8
// 422.849 us; speedup vs baseline: 1.2241x; 1.2241x over previous
//
#include <hip/hip_runtime.h>

typedef _Float16 h4 __attribute__((ext_vector_type(4)));
typedef _Float16 h8 __attribute__((ext_vector_type(8)));
typedef float f4 __attribute__((ext_vector_type(4)));

#define MFMA16(a, b, c) __builtin_amdgcn_mfma_f32_16x16x32_f16((a), (b), (c), 0, 0, 0)

static constexpr int TT  = 1024;
static constexpr int BS  = 1024;
static constexpr int LCH = 32;   // chunk length
static constexpr int NCH = 32;   // chunks
static constexpr size_t XTOT = (size_t)TT * BS * 128;

// workspace byte offsets
static constexpr size_t WS_WT16 = 0;       // 128x128 f16 : W_eff^T (S row-major)
static constexpr size_t WS_HF1  = 32768;   // 128x64  f16
static constexpr size_t WS_HF2  = 49152;   // 64x128  f16
static constexpr size_t WS_BW   = 65536;   // 128x64  f16
static constexpr size_t WS_EW   = 81920;   // 128x32  f16
static constexpr size_t WS_W32  = 90112;   // 128x128 f16 : (W^32)^T layout
static constexpr size_t WS_F    = 131072;                              // NCH slots f32
static constexpr size_t WS_INIT = WS_F + (size_t)NCH * BS * 128 * 4;   // NCH slots f32

template <typename T>
__device__ inline T ntload(const T* p) { return __builtin_nontemporal_load(p); }

// ---------------------------------------------------------------------------
// prep: W_eff (softmax+scale, stored transposed = S row-major) + f16 weights
// ---------------------------------------------------------------------------
__global__ void prep_kernel(const float* __restrict__ Aw, const float* __restrict__ As,
                            const float* __restrict__ hf1, const float* __restrict__ hf2,
                            const float* __restrict__ Bw, const float* __restrict__ Ew,
                            char* __restrict__ ws)
{
    const int tid = threadIdx.x;  // 128
    const int bid = blockIdx.x;   // 160
    if (bid < 128) {
        __shared__ float red[128];
        const int n = bid;
        const float a = Aw[n * 128 + tid];
        red[tid] = a;
        __syncthreads();
        for (int s = 64; s > 0; s >>= 1) {
            if (tid < s) red[tid] = fmaxf(red[tid], red[tid + s]);
            __syncthreads();
        }
        const float mx = red[0];
        __syncthreads();
        const float e = expf(a - mx);
        red[tid] = e;
        __syncthreads();
        for (int s = 64; s > 0; s >>= 1) {
            if (tid < s) red[tid] += red[tid + s];
            __syncthreads();
        }
        const float sm  = e / red[0];
        const float asv = As[n * 128 + tid];
        const float sc  = 1.0f - 0.1f * (1.0f / (1.0f + expf(-asv)));
        ((_Float16*)(ws + WS_WT16))[n * 128 + tid] = (_Float16)(sc * sm);
    } else {
        const int b2 = bid - 128;  // 32 blocks
        for (int i = b2 * 128 + tid; i < 8192; i += 32 * 128) {
            ((_Float16*)(ws + WS_HF1))[i] = (_Float16)hf1[i];
            ((_Float16*)(ws + WS_HF2))[i] = (_Float16)hf2[i];
            ((_Float16*)(ws + WS_BW))[i]  = (_Float16)Bw[i];
            if (i < 4096) ((_Float16*)(ws + WS_EW))[i] = (_Float16)Ew[i];
        }
    }
}

// ---------------------------------------------------------------------------
// W^32 via 5 dual-chain squarings (verified in R7): G=(W^T)^(2^s), H=G^T.
// ---------------------------------------------------------------------------
__global__ void w32_kernel(char* __restrict__ ws)
{
    const int tid  = threadIdx.x;
    const int lane = tid & 63;
    const int w    = tid >> 6;
    const int cl   = lane & 15;
    const int gq   = lane >> 4;
    constexpr int LDP = 136;

    __shared__ __align__(16) _Float16 G[2][128 * LDP];
    __shared__ __align__(16) _Float16 H[2][128 * LDP];

    const _Float16* Wt16 = (const _Float16*)(ws + WS_WT16);
    for (int i = tid; i < 2048; i += 256)
        *(h8*)&G[0][(i >> 4) * LDP + (i & 15) * 8] = *(const h8*)&Wt16[i * 8];
    __syncthreads();
    for (int i = tid; i < 16384; i += 256) {
        const int r = i >> 7, cc = i & 127;
        H[0][cc * LDP + r] = G[0][r * LDP + cc];
    }
    __syncthreads();

    int cur = 0;
    for (int s = 0; s < 5; ++s) {
        const _Float16* Gs = G[cur];
        const _Float16* Hs = H[cur];
        _Float16* Gd = G[cur ^ 1];
        _Float16* Hd = H[cur ^ 1];
        f4 aG[8][2], aH[8][2];
#pragma unroll
        for (int mt = 0; mt < 8; ++mt)
#pragma unroll
            for (int nt = 0; nt < 2; ++nt) { aG[mt][nt] = f4{}; aH[mt][nt] = f4{}; }
#pragma unroll
        for (int kk = 0; kk < 4; ++kk) {
            h8 bG0 = *(const h8*)&Hs[((w * 2 + 0) * 16 + cl) * LDP + kk * 32 + gq * 8];
            h8 bG1 = *(const h8*)&Hs[((w * 2 + 1) * 16 + cl) * LDP + kk * 32 + gq * 8];
            h8 bH0 = *(const h8*)&Gs[((w * 2 + 0) * 16 + cl) * LDP + kk * 32 + gq * 8];
            h8 bH1 = *(const h8*)&Gs[((w * 2 + 1) * 16 + cl) * LDP + kk * 32 + gq * 8];
#pragma unroll
            for (int mt = 0; mt < 8; ++mt) {
                h8 ag = *(const h8*)&Gs[(mt * 16 + cl) * LDP + kk * 32 + gq * 8];
                h8 ah = *(const h8*)&Hs[(mt * 16 + cl) * LDP + kk * 32 + gq * 8];
                aG[mt][0] = MFMA16(ag, bG0, aG[mt][0]);
                aG[mt][1] = MFMA16(ag, bG1, aG[mt][1]);
                aH[mt][0] = MFMA16(ah, bH0, aH[mt][0]);
                aH[mt][1] = MFMA16(ah, bH1, aH[mt][1]);
            }
        }
#pragma unroll
        for (int mt = 0; mt < 8; ++mt)
#pragma unroll
            for (int nt = 0; nt < 2; ++nt) {
                h4 hg, hh;
#pragma unroll
                for (int r = 0; r < 4; ++r) {
                    hg[r] = (_Float16)aG[mt][nt][r];
                    hh[r] = (_Float16)aH[mt][nt][r];
                }
                const int col  = (w * 2 + nt) * 16 + cl;
                const int rowb = mt * 16 + gq * 4;
                *(h4*)&Hd[col * LDP + rowb] = hg;
                *(h4*)&Gd[col * LDP + rowb] = hh;
            }
        __syncthreads();
        cur ^= 1;
    }
    _Float16* W32 = (_Float16*)(ws + WS_W32);
    for (int i = tid; i < 2048; i += 256)
        *(h8*)&W32[i * 8] = *(const h8*)&G[cur][(i >> 4) * LDP + (i & 15) * 8];
}

// ---------------------------------------------------------------------------
// fused_scan: block = one chunk (32 t) x 16 b, 4 waves n-split (R6 geometry).
// Per 4-step group: stage inputs -> G1/G2/G3 (drive in regs) -> 4 scan steps
// (state via double-buffered swizzled xsh, 1 barrier/step). No Drv array.
// FINAL=false: zero init, write F[c]. FINAL=true: init from Init[c], write X,Y.
// ---------------------------------------------------------------------------
template <bool FINAL>
__global__ __launch_bounds__(256, 2)
void fused_scan(const float* __restrict__ Mfl, const float* __restrict__ DTi,
                const float* __restrict__ Din, char* __restrict__ ws,
                float* __restrict__ Xout, float* __restrict__ Yout)
{
    const int tid  = threadIdx.x;
    const int lane = tid & 63;
    const int w    = tid >> 6;
    const int cl   = lane & 15;
    const int gq   = lane >> 4;
    const int bt   = blockIdx.x & 63;
    const int c    = blockIdx.x >> 6;
    const int b0   = bt * 16;

    const _Float16* Hf1  = (const _Float16*)(ws + WS_HF1);
    const _Float16* Hf2  = (const _Float16*)(ws + WS_HF2);
    const _Float16* Bw16 = (const _Float16*)(ws + WS_BW);
    const _Float16* Ew16 = (const _Float16*)(ws + WS_EW);
    const _Float16* Wt16 = (const _Float16*)(ws + WS_WT16);
    float* Fbuf          = (float*)(ws + WS_F);
    const float* Init    = (const float*)(ws + WS_INIT);

    __shared__ __align__(16) _Float16 mds[4][16 * 64];   // 8 KB
    __shared__ __align__(16) _Float16 dts[4][16 * 32];   // 4 KB
    __shared__ __align__(16) _Float16 hs[4][16 * 128];   // 16 KB
    __shared__ __align__(16) _Float16 us[4][16 * 64];    // 8 KB
    __shared__ __align__(16) _Float16 xsh[2][16 * 128];  // 8 KB

    // ---- MLP weight fragments (A-operands, n-split; R6-verified loads)
    h8 hf1f[2][2], bwf[2][2], ewf[2], hf2f[4];
#pragma unroll
    for (int nt = 0; nt < 2; ++nt) {
        const int ng = w * 32 + nt * 16 + cl;
#pragma unroll
        for (int kk = 0; kk < 2; ++kk) {
            hf1f[nt][kk] = *(const h8*)&Hf1[ng * 64 + kk * 32 + gq * 8];
            bwf[nt][kk]  = *(const h8*)&Bw16[ng * 64 + kk * 32 + gq * 8];
        }
        ewf[nt] = *(const h8*)&Ew16[ng * 32 + gq * 8];
    }
    {
        const int ng = w * 16 + cl;
#pragma unroll
        for (int kk = 0; kk < 4; ++kk)
            hf2f[kk] = *(const h8*)&Hf2[ng * 128 + kk * 32 + gq * 8];
    }
    // ---- scan W^T fragments, n-split (32 VGPR)
    h8 wfp[2][4];
#pragma unroll
    for (int nt = 0; nt < 2; ++nt)
#pragma unroll
        for (int kt = 0; kt < 4; ++kt)
            wfp[nt][kt] =
                *(const h8*)&Wt16[(w * 32 + nt * 16 + cl) * 128 + kt * 32 + gq * 8];

    // ---- state init into xsh[0]
    if constexpr (FINAL) {
        const int row = tid >> 4, c8 = tid & 15;
        const float* src = &Init[((size_t)c * BS + b0 + row) * 128 + c8 * 8];
        f4 v0 = *(const f4*)src, v1 = *(const f4*)(src + 4);
        h8 hv;
#pragma unroll
        for (int j = 0; j < 4; ++j) { hv[j] = (_Float16)v0[j]; hv[4 + j] = (_Float16)v1[j]; }
        *(h8*)&xsh[0][row * 128 + ((c8 ^ row) & 15) * 8] = hv;
    } else {
        h8 z = {};
        *(h8*)&xsh[0][tid * 8] = z;
    }

    // ---- input loads (group-ahead prefetch)
    const int qrow = (tid & 127) >> 3;
    const int qc4  = (tid & 7) * 4;
    f4 pm[4], pd[4];
    auto GLOAD = [&](int g) {
#pragma unroll
        for (int s = 0; s < 4; ++s) {
            const size_t t  = (size_t)c * LCH + g * 4 + s;
            const size_t rb = (t * BS + b0 + qrow) * 32 + qc4;
            pm[s] = (tid < 128) ? ntload((const f4*)&Mfl[rb]) : ntload((const f4*)&DTi[rb]);
            if (tid < 128) pd[s] = ntload((const f4*)&Din[rb]);
        }
    };
    GLOAD(0);

    _Float16* xcur = xsh[0];
    _Float16* xnxt = xsh[1];

    for (int g = 0; g < 8; ++g) {
        // ---- stage current group's inputs (f16, swizzled)
#pragma unroll
        for (int s = 0; s < 4; ++s) {
            const int col = (tid < 128) ? qc4 : (32 + qc4);
            h4 hv;
#pragma unroll
            for (int j = 0; j < 4; ++j) hv[j] = (_Float16)pm[s][j];
            *(h4*)&mds[s][qrow * 64 + (((col >> 3) ^ (qrow & 7)) * 8) + (col & 7)] = hv;
            if (tid < 128) {
                h4 h2;
#pragma unroll
                for (int j = 0; j < 4; ++j) h2[j] = (_Float16)pd[s][j];
                *(h4*)&dts[s][qrow * 32 + (((qc4 >> 3) ^ (qrow & 3)) * 8) + (qc4 & 7)] = h2;
            }
        }
        if (g < 7) GLOAD(g + 1);  // in flight across MLP+scan phases
        __syncthreads();

        // ---- G1: h^T = hf1 * md^T
#pragma unroll
        for (int s = 0; s < 4; ++s) {
            f4 ha0 = {}, ha1 = {};
#pragma unroll
            for (int kk = 0; kk < 2; ++kk) {
                h8 a = *(const h8*)&mds[s][cl * 64 + (((kk * 4 + gq) ^ (cl & 7)) * 8)];
                ha0 = MFMA16(hf1f[0][kk], a, ha0);
                ha1 = MFMA16(hf1f[1][kk], a, ha1);
            }
#pragma unroll
            for (int nt = 0; nt < 2; ++nt) {
                const int nb8 = w * 4 + nt * 2 + (gq >> 1);
                h4 hv;
#pragma unroll
                for (int r = 0; r < 4; ++r)
                    hv[r] = (_Float16)fmaxf(nt ? ha1[r] : ha0[r], 0.f);
                *(h4*)&hs[s][cl * 128 + ((nb8 ^ cl) & 15) * 8 + (gq & 1) * 4] = hv;
            }
        }
        __syncthreads();

        // ---- G2: u^T = hf2 * h^T
#pragma unroll
        for (int s = 0; s < 4; ++s) {
            f4 ua = {};
#pragma unroll
            for (int kt = 0; kt < 4; ++kt) {
                h8 a = *(const h8*)&hs[s][cl * 128 + (((kt * 4 + gq) ^ cl) & 15) * 8];
                ua = MFMA16(hf2f[kt], a, ua);
            }
            const int ub8 = w * 2 + (gq >> 1);
            h4 uv;
#pragma unroll
            for (int r = 0; r < 4; ++r) uv[r] = (_Float16)fmaxf(ua[r], 0.f);
            *(h4*)&us[s][cl * 64 + ((ub8 ^ (cl & 7)) & 7) * 8 + (gq & 1) * 4] = uv;
        }
        __syncthreads();

        // ---- G3: drive^T = Bw*u^T + Ew*D^T -> register h4 frags (scan C-layout)
        h4 dv[4][2];
#pragma unroll
        for (int s = 0; s < 4; ++s) {
            f4 a20 = {}, a21 = {};
#pragma unroll
            for (int kk = 0; kk < 2; ++kk) {
                h8 a = *(const h8*)&us[s][cl * 64 + (((kk * 4 + gq) ^ (cl & 7)) & 7) * 8];
                a20 = MFMA16(bwf[0][kk], a, a20);
                a21 = MFMA16(bwf[1][kk], a, a21);
            }
            {
                h8 ad = *(const h8*)&dts[s][cl * 32 + ((gq ^ (cl & 3)) * 8)];
                a20 = MFMA16(ewf[0], ad, a20);
                a21 = MFMA16(ewf[1], ad, a21);
            }
#pragma unroll
            for (int r = 0; r < 4; ++r) {
                dv[s][0][r] = (_Float16)a20[r];
                dv[s][1][r] = (_Float16)a21[r];
            }
        }

        // ---- scan 4 steps (cross-wave state via xsh, 1 barrier/step)
#pragma unroll
        for (int s = 0; s < 4; ++s) {
            h8 xf[4];
#pragma unroll
            for (int kt = 0; kt < 4; ++kt)
                xf[kt] = *(const h8*)&xcur[cl * 128 + (((kt * 4 + gq) ^ cl) & 15) * 8];
            f4 acc0, acc1;
#pragma unroll
            for (int r = 0; r < 4; ++r) {
                acc0[r] = (float)dv[s][0][r];
                acc1[r] = (float)dv[s][1][r];
            }
#pragma unroll
            for (int kt = 0; kt < 4; ++kt) {
                acc0 = MFMA16(wfp[0][kt], xf[kt], acc0);
                acc1 = MFMA16(wfp[1][kt], xf[kt], acc1);
            }

            if constexpr (FINAL) {
                const size_t t = (size_t)c * LCH + g * 4 + s;
                float* xp = &Xout[(t * BS + b0 + cl) * 128 + w * 32 + gq * 4];
                __builtin_nontemporal_store(acc0, (f4*)xp);
                __builtin_nontemporal_store(acc1, (f4*)(xp + 16));
                if (w == 3 && gq == 3)
                    __builtin_nontemporal_store(acc1[3], &Yout[t * BS + b0 + cl]);
            }
            const bool last = (g == 7) && (s == 3);
            if (!FINAL && last) {
                float* fp = &Fbuf[((size_t)c * BS + b0 + cl) * 128 + w * 32 + gq * 4];
                *(f4*)fp = acc0;
                *(f4*)(fp + 16) = acc1;
            }
            if (!last) {
#pragma unroll
                for (int nt = 0; nt < 2; ++nt) {
                    h4 hv;
#pragma unroll
                    for (int r = 0; r < 4; ++r) hv[r] = (_Float16)(nt ? acc1[r] : acc0[r]);
                    const int nb8 = w * 4 + nt * 2 + (gq >> 1);
                    *(h4*)&xnxt[cl * 128 + ((nb8 ^ cl) & 15) * 8 + (gq & 1) * 4] = hv;
                }
                __syncthreads();
                _Float16* tmp = xcur; xcur = xnxt; xnxt = tmp;
            }
        }
    }
}

// ---------------------------------------------------------------------------
// carry: Init[cc] = Init[cc-1] @ W^32 + F[cc-1], register style, 1 wave/block.
// ---------------------------------------------------------------------------
__global__ __launch_bounds__(64, 1)
void carry_kernel(const float* __restrict__ x0, char* __restrict__ ws,
                  int cc_lo, int n_steps, int copy0)
{
    const int lane = threadIdx.x;
    const int cl = lane & 15, gq = lane >> 4;
    const int b0 = blockIdx.x * 16;

    const _Float16* W32 = (const _Float16*)(ws + WS_W32);
    const float* Fbuf   = (const float*)(ws + WS_F);
    float* Init         = (float*)(ws + WS_INIT);

    __shared__ __align__(16) _Float16 tbuf[16 * 128];

    h8 wf[8][4];
#pragma unroll
    for (int nt = 0; nt < 8; ++nt)
#pragma unroll
        for (int kt = 0; kt < 4; ++kt)
            wf[nt][kt] = *(const h8*)&W32[(nt * 16 + cl) * 128 + kt * 32 + gq * 8];

    h8 xf[4];
    {
        f4 iv[8];
#pragma unroll
        for (int nt = 0; nt < 8; ++nt)
            iv[nt] = *(const f4*)&x0[(size_t)(b0 + cl) * 128 + nt * 16 + gq * 4];
        if (copy0) {
#pragma unroll
            for (int nt = 0; nt < 8; ++nt)
                *(f4*)&Init[((size_t)cc_lo * BS + b0 + cl) * 128 + nt * 16 + gq * 4] = iv[nt];
        }
#pragma unroll
        for (int nt = 0; nt < 8; ++nt) {
            h4 hv;
#pragma unroll
            for (int r = 0; r < 4; ++r) hv[r] = (_Float16)iv[nt][r];
            *(h4*)&tbuf[cl * 128 + (((nt * 2 + (gq >> 1)) ^ cl) & 15) * 8 + (gq & 1) * 4] = hv;
        }
#pragma unroll
        for (int kt = 0; kt < 4; ++kt)
            xf[kt] = *(const h8*)&tbuf[cl * 128 + (((kt * 4 + gq) ^ cl) & 15) * 8];
    }

    for (int i = 1; i <= n_steps; ++i) {
        const int cc = cc_lo + i;
        f4 acc[8];
#pragma unroll
        for (int nt = 0; nt < 8; ++nt)
            acc[nt] = *(const f4*)&Fbuf[((size_t)(cc - 1) * BS + b0 + cl) * 128 + nt * 16 + gq * 4];
#pragma unroll
        for (int kt = 0; kt < 4; ++kt)
#pragma unroll
            for (int nt = 0; nt < 8; ++nt)
                acc[nt] = MFMA16(wf[nt][kt], xf[kt], acc[nt]);
#pragma unroll
        for (int nt = 0; nt < 8; ++nt)
            *(f4*)&Init[((size_t)cc * BS + b0 + cl) * 128 + nt * 16 + gq * 4] = acc[nt];
        if (i < n_steps) {
#pragma unroll
            for (int nt = 0; nt < 8; ++nt) {
                h4 hv;
#pragma unroll
                for (int r = 0; r < 4; ++r) hv[r] = (_Float16)acc[nt][r];
                *(h4*)&tbuf[cl * 128 + (((nt * 2 + (gq >> 1)) ^ cl) & 15) * 8 + (gq & 1) * 4] = hv;
            }
#pragma unroll
            for (int kt = 0; kt < 4; ++kt)
                xf[kt] = *(const h8*)&tbuf[cl * 128 + (((kt * 4 + gq) ^ cl) & 15) * 8];
        }
    }
}

// ---------------------------------------------------------------------------
extern "C" void kernel_launch(void* const* d_in, const int* in_sizes, int n_in,
                              void* d_out, int out_size, void* d_ws, size_t ws_size,
                              hipStream_t stream)
{
    const float* x_in = (const float*)d_in[0];
    const float* Mfl  = (const float*)d_in[1];
    const float* DTi  = (const float*)d_in[2];
    const float* Din  = (const float*)d_in[3];
    const float* Aw   = (const float*)d_in[4];
    const float* As   = (const float*)d_in[5];
    const float* Bw   = (const float*)d_in[6];
    const float* Ew   = (const float*)d_in[7];
    const float* hf1  = (const float*)d_in[8];
    const float* hf2  = (const float*)d_in[9];
    char* ws    = (char*)d_ws;
    float* Xout = (float*)d_out;
    float* Yout = Xout + XTOT;

    prep_kernel<<<dim3(160), dim3(128), 0, stream>>>(Aw, As, hf1, hf2, Bw, Ew, ws);
    w32_kernel<<<dim3(1), dim3(256), 0, stream>>>(ws);

    // K1: fused MLP + local scan, chunks 0..30 -> F (no Drv materialization)
    fused_scan<false><<<dim3(31 * 64), dim3(256), 0, stream>>>(Mfl, DTi, Din, ws,
                                                               nullptr, nullptr);
    // K2: carry propagation -> Init[0..31]
    carry_kernel<<<dim3(64), dim3(64), 0, stream>>>(x_in, ws, 0, 31, 1);
    // K3: fused MLP + true scan -> X, Y
    fused_scan<true><<<dim3(32 * 64), dim3(256), 0, stream>>>(Mfl, DTi, Din, ws,
                                                              Xout, Yout);
}